// Round 10
// baseline (113.366 us; speedup 1.0000x reference)
//
#include <hip/hip_runtime.h>
#include <math.h>

// Problem constants (from reference setup_inputs)
#define Bn 16
#define Dn 512
#define Hn 96
#define Wn 96
#define Pn (Hn * Wn)   // 9216
#define Mn 128

#define DZ 4            // d-split for s_pix partials
#define DCH (Dn / DZ)   // 128 d's per block
#define PC 9            // p-chunks of 1024 for s_pix
#define NCHUNK 36       // p-chunks of 256 for finish
#define DG3 32          // d-rows per block in k_out -> grid (16,16) = 256 = 1/CU
#define NJ 9            // float4s per thread per row (2304/256)

// native vector type for nontemporal builtins (HIP float4 is a class type)
typedef float vfloat4 __attribute__((ext_vector_type(4)));

// ---------------------------------------------------------------------------
// Kernel 1: partial[b,dz,p] = sum_{d in dz-chunk} x[b,d,p] * wA[d]
// grid (Bn, PC, DZ) = (16,9,4) = 576 blocks, block 256.
// MEASURED (R7 diagnostic): 49.2us = 6.33 TB/s = copy ceiling. Do not touch.
// ---------------------------------------------------------------------------
__global__ void k_spix4(const float* __restrict__ x, const float* __restrict__ conv_w,
                        float* __restrict__ partial) {
    __shared__ float wA[DCH];
    const int b  = blockIdx.x;
    const int pc = blockIdx.y;
    const int dz = blockIdx.z;
    const int t  = threadIdx.x;
    if (t < DCH) wA[t] = conv_w[dz * DCH + t];   // wA = conv_w[:D] slice
    __syncthreads();

    const int p = pc * 1024 + t * 4;
    const float* xb = x + ((size_t)(b * Dn + dz * DCH)) * Pn + p;
    vfloat4 acc = {0.f, 0.f, 0.f, 0.f};
#pragma unroll 8
    for (int d = 0; d < DCH; ++d) {
        vfloat4 v = __builtin_nontemporal_load((const vfloat4*)(xb + (size_t)d * Pn));
        const float wv = wA[d];
        acc.x = fmaf(v.x, wv, acc.x);
        acc.y = fmaf(v.y, wv, acc.y);
        acc.z = fmaf(v.z, wv, acc.z);
        acc.w = fmaf(v.w, wv, acc.w);
    }
    *(vfloat4*)(partial + ((size_t)(b * DZ + dz)) * Pn + p) = acc;
}

// ---------------------------------------------------------------------------
// Kernel 2: s = sum_dz partial; w[b,p] = exp(s); pexp[b,chunk] = block expsum.
// Blocks with c<2 additionally compute E[b,d] = sum_m ef[b,m,d].
// No max-subtraction: it cancels exactly in softmax (s ~ N(0,0.5), no overflow).
// grid (Bn, NCHUNK) = 576 blocks, block 256.
// ---------------------------------------------------------------------------
__global__ void k_finish(const float* __restrict__ partial, const float* __restrict__ ef,
                         float* __restrict__ w, float* __restrict__ pexp,
                         float* __restrict__ E) {
    __shared__ float red[256];
    const int b = blockIdx.x;
    const int c = blockIdx.y;
    const int t = threadIdx.x;
    const int p = c * 256 + t;
    const size_t base = (size_t)b * DZ * Pn + p;
    const float s = partial[base] + partial[base + Pn] +
                    partial[base + 2 * Pn] + partial[base + 3 * Pn];
    const float e = __expf(s);
    w[b * Pn + p] = e;
    red[t] = e;
    __syncthreads();
    for (int o = 128; o > 0; o >>= 1) {
        if (t < o) red[t] += red[t + o];
        __syncthreads();
    }
    if (t == 0) pexp[b * NCHUNK + c] = red[0];

    if (c < 2) {
        const int d = c * 256 + t;
        const float* q = ef + (size_t)b * Mn * Dn + d;
        float sE = 0.f;
#pragma unroll 16
        for (int m = 0; m < Mn; ++m) sE += q[(size_t)m * Dn];
        E[b * Dn + d] = sE;
    }
}

// ---------------------------------------------------------------------------
// Kernel 3: out[(b*Dn+d)*Pn + p] = w[b,p] * (max(E[b,d],0)/denom[b])
// FILL-KERNEL SHAPE: grid (Bn,16) = 256 blocks = 1 block/CU; each block owns
// 32 contiguous d-rows = one 1.18 MB sequential write stream (the measured
// 7.0 TB/s fill pattern: few blocks, long streams, low occupancy).
// Per thread: 9 w float4 in regs (loaded once), then 32x9 streaming stores.
// ---------------------------------------------------------------------------
__global__ void k_out(const float* __restrict__ w, const float* __restrict__ E,
                      const float* __restrict__ pexp, float* __restrict__ out) {
    const int b  = blockIdx.x;
    const int dg = blockIdx.y * DG3;
    const int t  = threadIdx.x;

    float denom = 0.f;
#pragma unroll
    for (int j = 0; j < NCHUNK; ++j) denom += pexp[b * NCHUNK + j];
    const float inv = 1.f / denom;

    // load this thread's 9 w float4s once (36 VGPR)
    const vfloat4* w4 = (const vfloat4*)(w + b * Pn);
    vfloat4 wv[NJ];
#pragma unroll
    for (int j = 0; j < NJ; ++j) wv[j] = w4[t + 256 * j];

    vfloat4* o4 = (vfloat4*)(out + ((size_t)(b * Dn + dg)) * Pn);
    for (int r = 0; r < DG3; ++r) {
        const float evr = fmaxf(E[b * Dn + dg + r], 0.f) * inv;  // relu-hoist (exact: w>0)
        vfloat4* orow = o4 + (size_t)r * (Pn / 4);
#pragma unroll
        for (int j = 0; j < NJ; ++j) {
            orow[t + 256 * j] = wv[j] * evr;
        }
    }
}

// ---------------------------------------------------------------------------
extern "C" void kernel_launch(void* const* d_in, const int* in_sizes, int n_in,
                              void* d_out, int out_size, void* d_ws, size_t ws_size,
                              hipStream_t stream) {
    const float* x      = (const float*)d_in[0];   // (B, D, H, W)
    const float* ef     = (const float*)d_in[1];   // (B, M, D)
    const float* conv_w = (const float*)d_in[2];   // (2D,) -- only first D used
    // conv_b (d_in[3]) cancels in the softmax over p: unused.

    float* out = (float*)d_out;                    // (B, D, H, W)

    // ws layout (floats): w[Bn*Pn] | E[Bn*Dn] | partial[Bn*DZ*Pn] | pexp
    float* w       = (float*)d_ws;
    float* E       = w + Bn * Pn;
    float* partial = E + Bn * Dn;
    float* pexp    = partial + (size_t)Bn * DZ * Pn;
    (void)in_sizes; (void)n_in; (void)out_size; (void)ws_size;

    // K1: partial s_pix (302 MB read @ 6.33 TB/s measured = 49.2us, roofline)
    k_spix4<<<dim3(Bn, PC, DZ), dim3(256), 0, stream>>>(x, conv_w, partial);

    // K2: reduce partials -> exp(s), per-chunk expsums; + E colsum
    k_finish<<<dim3(Bn, NCHUNK), dim3(256), 0, stream>>>(partial, ef, w, pexp, E);

    // K3: out = w * relu(E)/denom (302 MB, fill-shaped: 256 long streams)
    k_out<<<dim3(Bn, Dn / DG3), dim3(256), 0, stream>>>(w, E, pexp, out);
}

// Round 11
// 107.915 us; speedup vs baseline: 1.0505x; 1.0505x over previous
//
#include <hip/hip_runtime.h>
#include <math.h>

// Problem constants (from reference setup_inputs)
#define Bn 16
#define Dn 512
#define Hn 96
#define Wn 96
#define Pn (Hn * Wn)   // 9216
#define Mn 128

#define DZ 4            // d-split for s_pix partials
#define DCH (Dn / DZ)   // 128 d's per block
#define PC 9            // p-chunks of 1024 for s_pix
#define NCHUNK 36       // p-chunks of 256 for finish
#define NCOL 2          // dedicated colsum blocks per batch (256 d each)
#define DG 4            // d-rows per block in k_out -> 2048 blocks = 8/CU exact
#define NJ 9            // float4s per thread per row (2304/256)

// native vector type for nontemporal builtins (HIP float4 is a class type)
typedef float vfloat4 __attribute__((ext_vector_type(4)));

// ---------------------------------------------------------------------------
// Kernel 1: partial[b,dz,p] = sum_{d in dz-chunk} x[b,d,p] * wA[d]
// grid (Bn, PC, DZ) = (16,9,4) = 576 blocks, block 256.
// MEASURED (R7): 49.2us = 6.33 TB/s = copy ceiling. FROZEN.
// ---------------------------------------------------------------------------
__global__ void k_spix4(const float* __restrict__ x, const float* __restrict__ conv_w,
                        float* __restrict__ partial) {
    __shared__ float wA[DCH];
    const int b  = blockIdx.x;
    const int pc = blockIdx.y;
    const int dz = blockIdx.z;
    const int t  = threadIdx.x;
    if (t < DCH) wA[t] = conv_w[dz * DCH + t];   // wA = conv_w[:D] slice
    __syncthreads();

    const int p = pc * 1024 + t * 4;
    const float* xb = x + ((size_t)(b * Dn + dz * DCH)) * Pn + p;
    vfloat4 acc = {0.f, 0.f, 0.f, 0.f};
#pragma unroll 8
    for (int d = 0; d < DCH; ++d) {
        vfloat4 v = __builtin_nontemporal_load((const vfloat4*)(xb + (size_t)d * Pn));
        const float wv = wA[d];
        acc.x = fmaf(v.x, wv, acc.x);
        acc.y = fmaf(v.y, wv, acc.y);
        acc.z = fmaf(v.z, wv, acc.z);
        acc.w = fmaf(v.w, wv, acc.w);
    }
    *(vfloat4*)(partial + ((size_t)(b * DZ + dz)) * Pn + p) = acc;
}

// ---------------------------------------------------------------------------
// Kernel 2: grid (Bn, NCHUNK+NCOL) = (16,38), block 256.
//  c <  NCHUNK: s = sum_dz partial; w = exp(s); pexp[b,c] = chunk expsum.
//  c >= NCHUNK: DEDICATED colsum blocks: E[b,d] = sum_m ef[b,m,d]
//               (moved off the softmax blocks so no straggler tail).
// No max-subtraction: cancels exactly in softmax (s ~ N(0,0.5), no overflow).
// ---------------------------------------------------------------------------
__global__ void k_finish(const float* __restrict__ partial, const float* __restrict__ ef,
                         float* __restrict__ w, float* __restrict__ pexp,
                         float* __restrict__ E) {
    __shared__ float red[256];
    const int b = blockIdx.x;
    const int c = blockIdx.y;
    const int t = threadIdx.x;

    if (c < NCHUNK) {
        const int p = c * 256 + t;
        const size_t base = (size_t)b * DZ * Pn + p;
        const float s = __builtin_nontemporal_load(&partial[base]) +
                        __builtin_nontemporal_load(&partial[base + Pn]) +
                        __builtin_nontemporal_load(&partial[base + 2 * Pn]) +
                        __builtin_nontemporal_load(&partial[base + 3 * Pn]);
        const float e = __expf(s);
        w[b * Pn + p] = e;
        red[t] = e;
        __syncthreads();
        for (int o = 128; o > 0; o >>= 1) {
            if (t < o) red[t] += red[t + o];
            __syncthreads();
        }
        if (t == 0) pexp[b * NCHUNK + c] = red[0];
    } else {
        const int d = (c - NCHUNK) * 256 + t;
        const float* q = ef + (size_t)b * Mn * Dn + d;
        float sE = 0.f;
#pragma unroll 16
        for (int m = 0; m < Mn; ++m) sE += q[(size_t)m * Dn];
        E[b * Dn + d] = sE;
    }
}

// ---------------------------------------------------------------------------
// Kernel 3: out[(b*Dn+d)*Pn + p] = w[b,p] * (max(E[b,d],0)/denom[b])
// (exact relu-hoist: w>0, denom>0). R9 config — best measured (109.4 total).
// w chunk in registers (9 float4/thread, loaded once); r-outer sequential
// 144 KB write stream per block. grid (Bn, Dn/DG) = 2048 = 8/CU exact.
// ---------------------------------------------------------------------------
__global__ void k_out(const float* __restrict__ w, const float* __restrict__ E,
                      const float* __restrict__ pexp, float* __restrict__ out) {
    const int b  = blockIdx.x;
    const int dg = blockIdx.y * DG;
    const int t  = threadIdx.x;

    float denom = 0.f;
#pragma unroll
    for (int j = 0; j < NCHUNK; ++j) denom += pexp[b * NCHUNK + j];
    const float inv = 1.f / denom;

    const vfloat4* w4 = (const vfloat4*)(w + b * Pn);
    vfloat4 wv[NJ];
#pragma unroll
    for (int j = 0; j < NJ; ++j) wv[j] = w4[t + 256 * j];

    vfloat4* o4 = (vfloat4*)(out + ((size_t)(b * Dn + dg)) * Pn);
#pragma unroll
    for (int r = 0; r < DG; ++r) {
        const float evr = fmaxf(E[b * Dn + dg + r], 0.f) * inv;
        vfloat4* orow = o4 + (size_t)r * (Pn / 4);
#pragma unroll
        for (int j = 0; j < NJ; ++j) {
            orow[t + 256 * j] = wv[j] * evr;
        }
    }
}

// ---------------------------------------------------------------------------
extern "C" void kernel_launch(void* const* d_in, const int* in_sizes, int n_in,
                              void* d_out, int out_size, void* d_ws, size_t ws_size,
                              hipStream_t stream) {
    const float* x      = (const float*)d_in[0];   // (B, D, H, W)
    const float* ef     = (const float*)d_in[1];   // (B, M, D)
    const float* conv_w = (const float*)d_in[2];   // (2D,) -- only first D used
    // conv_b (d_in[3]) cancels in the softmax over p: unused.

    float* out = (float*)d_out;                    // (B, D, H, W)

    // ws layout (floats): w[Bn*Pn] | E[Bn*Dn] | partial[Bn*DZ*Pn] | pexp
    float* w       = (float*)d_ws;
    float* E       = w + Bn * Pn;
    float* partial = E + Bn * Dn;
    float* pexp    = partial + (size_t)Bn * DZ * Pn;
    (void)in_sizes; (void)n_in; (void)out_size; (void)ws_size;

    // K1: partial s_pix (302 MB read @ 6.33 TB/s measured; roofline, frozen)
    k_spix4<<<dim3(Bn, PC, DZ), dim3(256), 0, stream>>>(x, conv_w, partial);

    // K2: softmax chunks + dedicated colsum blocks (no straggler tail)
    k_finish<<<dim3(Bn, NCHUNK + NCOL), dim3(256), 0, stream>>>(partial, ef, w, pexp, E);

    // K3: out = w * relu(E)/denom (302 MB write; R9-best config)
    k_out<<<dim3(Bn, Dn / DG), dim3(256), 0, stream>>>(w, E, pexp, out);
}

// Round 12
// 100.197 us; speedup vs baseline: 1.1314x; 1.0770x over previous
//
#include <hip/hip_runtime.h>
#include <math.h>

// Problem constants (from reference setup_inputs)
#define Bn 16
#define Dn 512
#define Hn 96
#define Wn 96
#define Pn (Hn * Wn)   // 9216
#define Mn 128

#define NCHUNK 9        // p-chunks of 1024 (256 float4 columns per chunk)
#define SUBG 4          // d-subgroups inside the 1024-thread block
#define DCH (Dn / SUBG) // 128 d's per subgroup (same as R4's proven DCH)
#define DG 4            // d-rows per block in k_out -> 2048 blocks = 8/CU exact
#define NJ 9            // float4s per thread per row in k_out (2304/256)

// native vector type for nontemporal builtins (HIP float4 is a class type)
typedef float vfloat4 __attribute__((ext_vector_type(4)));

// ---------------------------------------------------------------------------
// Kernel 1 (fused K1+K2): grid (Bn, NCHUNK+1), block 1024.
//  pc < NCHUNK: 4 subgroups of 256 threads each run R4's EXACT proven load
//    pattern (subgroup sg covers d in [sg*128,(sg+1)*128), float4 over p);
//    dz-combine in LDS; subgroup 0 does exp, writes w, block-reduce -> pexp.
//    (no partial array, no separate K2 phase)
//  pc == NCHUNK: colsum blocks: E[b,d] = sum_m ef[b,m,d]  (512 active thr).
// No max-subtraction: cancels exactly in softmax (s ~ N(0,0.5), no overflow).
// ---------------------------------------------------------------------------
__global__ void k_spix_fused(const float* __restrict__ x, const float* __restrict__ conv_w,
                             const float* __restrict__ ef,
                             float* __restrict__ w, float* __restrict__ pexp,
                             float* __restrict__ E) {
    const int b  = blockIdx.x;
    const int pc = blockIdx.y;
    const int t  = threadIdx.x;          // 0..1023

    if (pc < NCHUNK) {
        __shared__ float   wA_s[Dn];
        __shared__ vfloat4 acc_s[SUBG - 1][256];
        __shared__ float   red[256];
        const int sg = t >> 8;           // d-subgroup 0..3
        const int tt = t & 255;          // p-column within chunk
        if (t < Dn) wA_s[t] = conv_w[t];     // wA = conv_w[:D]
        __syncthreads();

        const int p = pc * 1024 + tt * 4;
        const float* xb = x + ((size_t)(b * Dn + sg * DCH)) * Pn + p;
        vfloat4 acc = {0.f, 0.f, 0.f, 0.f};
#pragma unroll 8
        for (int d = 0; d < DCH; ++d) {
            vfloat4 v = __builtin_nontemporal_load((const vfloat4*)(xb + (size_t)d * Pn));
            const float wv = wA_s[sg * DCH + d];
            acc.x = fmaf(v.x, wv, acc.x);
            acc.y = fmaf(v.y, wv, acc.y);
            acc.z = fmaf(v.z, wv, acc.z);
            acc.w = fmaf(v.w, wv, acc.w);
        }
        if (sg > 0) acc_s[sg - 1][tt] = acc;
        __syncthreads();
        if (sg == 0) {
            vfloat4 s4 = acc + acc_s[0][tt] + acc_s[1][tt] + acc_s[2][tt];
            vfloat4 e4;
            e4.x = __expf(s4.x);
            e4.y = __expf(s4.y);
            e4.z = __expf(s4.z);
            e4.w = __expf(s4.w);
            *(vfloat4*)(w + b * Pn + p) = e4;
            red[tt] = (e4.x + e4.y) + (e4.z + e4.w);
        }
        __syncthreads();
        for (int o = 128; o > 0; o >>= 1) {
            if (t < o) red[t] += red[t + o];
            __syncthreads();
        }
        if (t == 0) pexp[b * NCHUNK + pc] = red[0];
    } else {
        // dedicated colsum blocks (one per batch): E[b,d] = sum_m ef[b,m,d]
        if (t < Dn) {
            const float* q = ef + (size_t)b * Mn * Dn + t;
            float sE = 0.f;
#pragma unroll 16
            for (int m = 0; m < Mn; ++m) sE += q[(size_t)m * Dn];
            E[b * Dn + t] = sE;
        }
    }
}

// ---------------------------------------------------------------------------
// Kernel 2: out[(b*Dn+d)*Pn + p] = w[b,p] * (max(E[b,d],0)/denom[b])
// (exact relu-hoist: w>0, denom>0). R9/R11-best config, untouched except
// denom now sums NCHUNK=9 pexp values.
// grid (Bn, Dn/DG) = 2048 blocks = 8/CU exact, block 256.
// ---------------------------------------------------------------------------
__global__ void k_out(const float* __restrict__ w, const float* __restrict__ E,
                      const float* __restrict__ pexp, float* __restrict__ out) {
    const int b  = blockIdx.x;
    const int dg = blockIdx.y * DG;
    const int t  = threadIdx.x;

    float denom = 0.f;
#pragma unroll
    for (int j = 0; j < NCHUNK; ++j) denom += pexp[b * NCHUNK + j];
    const float inv = 1.f / denom;

    const vfloat4* w4 = (const vfloat4*)(w + b * Pn);
    vfloat4 wv[NJ];
#pragma unroll
    for (int j = 0; j < NJ; ++j) wv[j] = w4[t + 256 * j];

    vfloat4* o4 = (vfloat4*)(out + ((size_t)(b * Dn + dg)) * Pn);
#pragma unroll
    for (int r = 0; r < DG; ++r) {
        const float evr = fmaxf(E[b * Dn + dg + r], 0.f) * inv;
        vfloat4* orow = o4 + (size_t)r * (Pn / 4);
#pragma unroll
        for (int j = 0; j < NJ; ++j) {
            orow[t + 256 * j] = wv[j] * evr;
        }
    }
}

// ---------------------------------------------------------------------------
extern "C" void kernel_launch(void* const* d_in, const int* in_sizes, int n_in,
                              void* d_out, int out_size, void* d_ws, size_t ws_size,
                              hipStream_t stream) {
    const float* x      = (const float*)d_in[0];   // (B, D, H, W)
    const float* ef     = (const float*)d_in[1];   // (B, M, D)
    const float* conv_w = (const float*)d_in[2];   // (2D,) -- only first D used
    // conv_b (d_in[3]) cancels in the softmax over p: unused.

    float* out = (float*)d_out;                    // (B, D, H, W)

    // ws layout (floats): w[Bn*Pn] | E[Bn*Dn] | pexp[Bn*NCHUNK]
    float* w    = (float*)d_ws;
    float* E    = w + Bn * Pn;
    float* pexp = E + Bn * Dn;
    (void)in_sizes; (void)n_in; (void)out_size; (void)ws_size;

    // K1'': s_pix + softmax-exp + chunk sums + E colsum, one kernel
    // (302 MB read @ measured ceiling; R4's exact load pattern per subgroup)
    k_spix_fused<<<dim3(Bn, NCHUNK + 1), dim3(1024), 0, stream>>>(
        x, conv_w, ef, w, pexp, E);

    // K2: out = w * relu(E)/denom (302 MB write; best-known config)
    k_out<<<dim3(Bn, Dn / DG), dim3(256), 0, stream>>>(w, E, pexp, out);
}